// Round 12
// baseline (338.894 us; speedup 1.0000x reference)
//
#include <hip/hip_runtime.h>
#include <hip/hip_bf16.h>

#define B_ 32
#define S_ 2048
#define D_ 1024

// 256x128 tile, BK=32, 8 waves (4Mx2N, 64x64 each), double-buffered 48KB LDS
// -> 2 blocks/CU. One vmcnt(0)+barrier per K-tile (R11 body on R8 geometry).
#define BM 256
#define BN 128
#define BK 32
#define NKT (D_ / BK)   // 32 K-tiles

typedef __attribute__((ext_vector_type(8))) short bf16x8;
typedef __attribute__((ext_vector_type(4))) float f32x4;
typedef __attribute__((ext_vector_type(4))) float float4v;

#define AS1 __attribute__((address_space(1)))
#define AS3 __attribute__((address_space(3)))

// f32 -> bf16 round-to-nearest-even on raw bits
__device__ __forceinline__ short f2bf(float f) {
    union { float f; unsigned u; } uf;
    uf.f = f;
    unsigned u = uf.u;
    u += 0x7FFFu + ((u >> 16) & 1u);
    return (short)(u >> 16);
}

// ---------------- pre-convert: f32 -> bf16, 8 floats/thread ----------------
__global__ __launch_bounds__(256) void cvt_bf16(const float4v* __restrict__ src,
                                                bf16x8* __restrict__ dst, int n8) {
    const int stride = gridDim.x * blockDim.x;
    for (int i = blockIdx.x * blockDim.x + threadIdx.x; i < n8; i += stride) {
        float4v a = src[2 * i], b = src[2 * i + 1];
        bf16x8 v;
#pragma unroll
        for (int j = 0; j < 4; ++j) {
            v[j]     = f2bf(a[j]);
            v[4 + j] = f2bf(b[j]);
        }
        dst[i] = v;
    }
}

// ============================================================================
// LDS swizzle (64B rows, BK=32): stored byte = (r*64 + c) ^ ((r&7)<<4)
// [R8-proven, refcheck'd]. Staging: linear gll dest (tid*16) + inverse-mapped
// global source. Body (R11-proven): stage tile t+1 || compute tile t
// (compiler-scheduled), then ONE vmcnt(0)+s_barrier boundary.
// Safety: each wave's ds_reads are consumed by MFMA-gating lgkm waits before
// the barrier, so the boundary separates buf-Y readers (t-1) from buf-Y
// stagers (t+1); vmcnt(0) retires t+1's stages before anyone reads buf Y.
// ============================================================================

// ---- stage tile kt into buffer SB: A rows 0-127, A rows 128-255, B (3 gll) --
#define STAGE(SB, kt) do {                                                     \
    const __hip_bfloat16* _ga0 = aBase + (size_t)srow * D_ + (kt) * BK + scol; \
    __builtin_amdgcn_global_load_lds((const AS1 unsigned int*)_ga0,            \
        (AS3 unsigned int*)((char*)&As[SB][0] + tid * 16), 16, 0, 0);          \
    const __hip_bfloat16* _ga1 = aBase + (size_t)(srow + 128) * D_ + (kt) * BK + scol; \
    __builtin_amdgcn_global_load_lds((const AS1 unsigned int*)_ga1,            \
        (AS3 unsigned int*)((char*)&As[SB][0] + 8192 + tid * 16), 16, 0, 0);   \
    const __hip_bfloat16* _gb = bBase + (size_t)srow * D_ + (kt) * BK + scol;  \
    __builtin_amdgcn_global_load_lds((const AS1 unsigned int*)_gb,             \
        (AS3 unsigned int*)((char*)&Bs[SB][0] + tid * 16), 16, 0, 0);          \
} while (0)

// ---- compute one K-tile from buffer CB: 8 ds_read_b128, 16 MFMA ----
#define COMPUTE(CB) do {                                                       \
    bf16x8 _af[4], _bv[4];                                                     \
    _Pragma("unroll")                                                          \
    for (int _mi = 0; _mi < 4; ++_mi)                                          \
        _af[_mi] = *(const bf16x8*)((const char*)&As[CB][0] + aRd + _mi * 1024); \
    _Pragma("unroll")                                                          \
    for (int _ni = 0; _ni < 4; ++_ni)                                          \
        _bv[_ni] = *(const bf16x8*)((const char*)&Bs[CB][0] + bRd + _ni * 1024); \
    __builtin_amdgcn_s_setprio(1);                                             \
    _Pragma("unroll")                                                          \
    for (int _mi = 0; _mi < 4; ++_mi)                                          \
        _Pragma("unroll")                                                      \
        for (int _ni = 0; _ni < 4; ++_ni)                                      \
            acc[_mi][_ni] = __builtin_amdgcn_mfma_f32_16x16x32_bf16(           \
                _af[_mi], _bv[_ni], acc[_mi][_ni], 0, 0, 0);                   \
    __builtin_amdgcn_s_setprio(0); } while (0)

#define BOUND() do {                                          \
    asm volatile("s_waitcnt vmcnt(0)" ::: "memory");          \
    asm volatile("s_barrier" ::: "memory"); } while (0)

// body: stage tile kn into buf Y || compute tile from buf X; boundary
#define BODY(X, Y, kn) do { STAGE(Y, kn); COMPUTE(X); BOUND(); } while (0)
#define BODY_LAST(X)   do { COMPUTE(X); } while (0)

__global__ __launch_bounds__(512, 4) void fused_gemm_bf16(
    const __hip_bfloat16* __restrict__ aBf,   // [B][S][D] bf16 (pre-converted)
    const __hip_bfloat16* __restrict__ wBf,   // [3][D][D] bf16 (pre-converted)
    const int*   __restrict__ scale_id,
    const int*   __restrict__ mask,
    const float* __restrict__ bias,
    const float* __restrict__ scemb,
    const float* __restrict__ bremb,
    float*       __restrict__ out,
    float*       __restrict__ colws)
{
    __shared__ __align__(16) short As[2][BM * BK];   // 2 x 16 KB
    __shared__ __align__(16) short Bs[2][BN * BK];   // 2 x  8 KB  (48 KB total)

    const int tid = threadIdx.x;
    const int lane = tid & 63;
    const int wid = tid >> 6;                  // 0..7
    const int wm = wid >> 1, wn = wid & 1;     // 4x2 waves, 64x64 each

    // chunked XCD swizzle (NWG = 2048, divisible by 8); nt fastest
    const int NTI = D_ / BN;  // 8
    const int MTI = S_ / BM;  // 8
    const int NWG = B_ * MTI * NTI;
    const int CPX = NWG / 8;
    int lid = ((int)blockIdx.x % 8) * CPX + ((int)blockIdx.x / 8);
    int nt = lid % NTI;
    int mt = (lid / NTI) % MTI;
    int bb = lid / (NTI * MTI);

    const int sid = scale_id[bb];
    const __hip_bfloat16* aBase = aBf + ((size_t)bb * S_ + (size_t)mt * BM) * D_;
    const __hip_bfloat16* bBase = wBf + ((size_t)sid * D_ + (size_t)nt * BN) * D_;

    // staging inverse map [R8-proven]: thread's LDS dest = tid*16 (linear);
    // recover the logical (row, slot) whose swizzled address equals it.
    const int l5 = tid & 31;                           // 16B-chunk idx in 512B
    const int ir0 = ((l5 >> 2) ^ (l5 >> 4)) & 1;
    const int ir1 = (l5 >> 3) & 1;
    const int ir2 = (l5 >> 4) & 1;
    const int is1 = ((l5 >> 1) ^ (l5 >> 3)) & 1;
    const int is0 = (l5 ^ (l5 >> 2) ^ (l5 >> 4)) & 1;
    const int srow = (tid >> 5) * 8 + ir2 * 4 + ir1 * 2 + ir0;   // 0..127
    const int scol = (is1 * 2 + is0) * 8;                        // bf16 col

    // read-side swizzled base addrs
    const int fr = lane & 15;
    const int fg = lane >> 4;
    const int aRd = (((wm * 64 + fr) * 64) + fg * 16) ^ ((fr & 7) << 4);
    const int bRd = (((wn * 64 + fr) * 64) + fg * 16) ^ ((fr & 7) << 4);

    f32x4 acc[4][4];
#pragma unroll
    for (int mi = 0; mi < 4; ++mi)
#pragma unroll
        for (int ni = 0; ni < 4; ++ni)
            acc[mi][ni] = (f32x4){0.f, 0.f, 0.f, 0.f};

    // prologue: tile 0 -> buf 0; full retire before first read
    STAGE(0, 0);
    BOUND();

#pragma unroll 1
    for (int kt = 0; kt < NKT - 2; kt += 2) {
        BODY(0, 1, kt + 1);
        BODY(1, 0, kt + 2);
    }
    BODY(0, 1, NKT - 1);   // tile 30 (buf0), stages tile 31 -> buf1, boundary
    BODY_LAST(1);          // tile 31 (buf1), no staging

    __syncthreads();       // lgkm drain; LDS reusable

    // ---- epilogue phase 1: silu + scale_embed in-register, masked colsums ----
    // acc[mi][ni]: row = wm*64 + mi*16 + fg*4 + r;  col = wn*64 + ni*16 + fr
    const int colb = nt * BN;
    float bv[4], sv[4];
#pragma unroll
    for (int ni = 0; ni < 4; ++ni) {
        const int n = colb + wn * 64 + ni * 16 + fr;
        bv[ni] = bias[sid * D_ + n];
        sv[ni] = scemb[sid * D_ + n];
    }

    float colsum[4] = {0.f, 0.f, 0.f, 0.f};
#pragma unroll
    for (int mi = 0; mi < 4; ++mi) {
        const int mrow0 = mt * BM + wm * 64 + mi * 16 + fg * 4;
        float mk[4];
#pragma unroll
        for (int r = 0; r < 4; ++r)
            mk[r] = (mask[(size_t)bb * S_ + mrow0 + r] > 0) ? 1.f : 0.f;
#pragma unroll
        for (int ni = 0; ni < 4; ++ni)
#pragma unroll
            for (int r = 0; r < 4; ++r) {
                const float v = acc[mi][ni][r] + bv[ni];
                const float o = v / (1.f + __expf(-v)) + sv[ni];  // silu + scale_embed
                acc[mi][ni][r] = o;
                colsum[ni] += mk[r] * o;
            }
    }

#pragma unroll
    for (int ni = 0; ni < 4; ++ni) {
        float s = colsum[ni];
        s += __shfl_xor(s, 16);
        s += __shfl_xor(s, 32);
        if (fg == 0) {
            const int n = colb + wn * 64 + ni * 16 + fr;
            atomicAdd(&colws[(size_t)bb * D_ + n], s);
        }
    }

    // ---- epilogue phase 2: LDS bounce -> 128B-contiguous float4 stores ----
    // ldsF[64][132] f32 = 33.8 KB (fits in the 48 KB LDS block). Per mi round:
    // 64-row x 128-col slab; stores in 4 col-quarters, 8 lanes x 16B = 128B.
    float* ldsF = (float*)&As[0][0];
    const int lr = tid >> 3;      // 0..63 read row
    const int c8 = tid & 7;       // col-quad within quarter

    float4v b0q[4], b1q[4];
#pragma unroll
    for (int q = 0; q < 4; ++q) {
        const int gcol = colb + q * 32 + c8 * 4;
        b0q[q] = *(const float4v*)&bremb[0 * D_ + gcol];
        b1q[q] = *(const float4v*)&bremb[1 * D_ + gcol];
    }

    const size_t MIDOFF = (size_t)B_ * S_ * D_;

#pragma unroll
    for (int mi = 0; mi < 4; ++mi) {
#pragma unroll
        for (int ni = 0; ni < 4; ++ni)
#pragma unroll
            for (int r = 0; r < 4; ++r)
                ldsF[(wm * 16 + fg * 4 + r) * 132 + wn * 64 + ni * 16 + fr] =
                    acc[mi][ni][r];
        __syncthreads();

        const int grow = mt * BM + (lr >> 4) * 64 + mi * 16 + (lr & 15);
        const size_t rowbase = ((size_t)bb * S_ + grow) * D_ + colb;
#pragma unroll
        for (int q = 0; q < 4; ++q) {
            float4v v = *(const float4v*)&ldsF[lr * 132 + q * 32 + c8 * 4];
            __builtin_nontemporal_store(v + b0q[q], (float4v*)&out[rowbase + q * 32 + c8 * 4]);
            __builtin_nontemporal_store(v + b1q[q], (float4v*)&out[MIDOFF + rowbase + q * 32 + c8 * 4]);
        }
        __syncthreads();
    }
}

// ---------------- fallback path (f32 reg-staging, 128^2, 2-barrier) --------
#define FBM 128
#define FBN 128
#define FBK 64
#define FNK (D_ / FBK)

__global__ __launch_bounds__(256, 2) void fused_gemm_f32(
    const float* __restrict__ midi,
    const int*   __restrict__ scale_id,
    const int*   __restrict__ mask,
    const float* __restrict__ W,
    const float* __restrict__ bias,
    const float* __restrict__ scemb,
    const float* __restrict__ bremb,
    float*       __restrict__ out,
    float*       __restrict__ ws)
{
    __shared__ __align__(16) short Asf[FBM * FBK];
    __shared__ __align__(16) short Bsf[FBM * FBK];

    const int tid = threadIdx.x;
    const int NTI = D_ / FBN;
    const int MTI = S_ / FBM;
    const int NWG = B_ * MTI * NTI;
    const int CPX = NWG / 8;
    int lid = ((int)blockIdx.x % 8) * CPX + ((int)blockIdx.x / 8);
    int nt = lid % NTI;
    int mt = (lid / NTI) % MTI;
    int bb = lid / (NTI * MTI);

    const int sid = scale_id[bb];
    const float* aBase = midi + ((size_t)bb * S_ + (size_t)mt * FBM) * D_;
    const float* bBase = W + ((size_t)sid * D_ + (size_t)nt * FBN) * D_;

    const int r0 = tid >> 3;
    const int kp = (tid & 7) * 8;

    float4v aL[4], aH[4], bL[4], bH[4];

    auto load_regs = [&](int kt) {
        const int kc = kt * FBK + kp;
#pragma unroll
        for (int i = 0; i < 4; ++i) {
            const float* pa = aBase + (size_t)(r0 + 32 * i) * D_ + kc;
            aL[i] = *(const float4v*)pa;
            aH[i] = *(const float4v*)(pa + 4);
            const float* pb = bBase + (size_t)(r0 + 32 * i) * D_ + kc;
            bL[i] = *(const float4v*)pb;
            bH[i] = *(const float4v*)(pb + 4);
        }
    };

    auto write_lds = [&]() {
#pragma unroll
        for (int i = 0; i < 4; ++i) {
            const int row = r0 + 32 * i;
            const int off = (row * FBK + kp) ^ ((row & 7) << 3);
            bf16x8 va, vb;
#pragma unroll
            for (int j = 0; j < 4; ++j) {
                va[j]     = f2bf(aL[i][j]);
                va[4 + j] = f2bf(aH[i][j]);
                vb[j]     = f2bf(bL[i][j]);
                vb[4 + j] = f2bf(bH[i][j]);
            }
            *(bf16x8*)&Asf[off] = va;
            *(bf16x8*)&Bsf[off] = vb;
        }
    };

    f32x4 acc[4][4];
#pragma unroll
    for (int mi = 0; mi < 4; ++mi)
#pragma unroll
        for (int ni = 0; ni < 4; ++ni)
            acc[mi][ni] = (f32x4){0.f, 0.f, 0.f, 0.f};

    const int lane = tid & 63;
    const int wid = tid >> 6;
    const int wm = wid >> 1, wn = wid & 1;
    const int fr = lane & 15;
    const int fg = lane >> 4;

    load_regs(0);
    write_lds();
    __syncthreads();

    for (int kt = 0; kt < FNK; ++kt) {
        if (kt + 1 < FNK) load_regs(kt + 1);
#pragma unroll
        for (int kk = 0; kk < 2; ++kk) {
            bf16x8 af[4], bfr[4];
#pragma unroll
            for (int mi = 0; mi < 4; ++mi) {
                const int row = wm * 64 + mi * 16 + fr;
                const int off = (row * FBK + kk * 32 + fg * 8) ^ ((row & 7) << 3);
                af[mi] = *(const bf16x8*)&Asf[off];
            }
#pragma unroll
            for (int ni = 0; ni < 4; ++ni) {
                const int row = wn * 64 + ni * 16 + fr;
                const int off = (row * FBK + kk * 32 + fg * 8) ^ ((row & 7) << 3);
                bfr[ni] = *(const bf16x8*)&Bsf[off];
            }
#pragma unroll
            for (int mi = 0; mi < 4; ++mi)
#pragma unroll
                for (int ni = 0; ni < 4; ++ni)
                    acc[mi][ni] = __builtin_amdgcn_mfma_f32_16x16x32_bf16(
                        af[mi], bfr[ni], acc[mi][ni], 0, 0, 0);
        }
        __syncthreads();
        if (kt + 1 < FNK) write_lds();
        __syncthreads();
    }

    const int ncolbase = nt * FBN + wn * 64;
    float bv[4], sv[4], b0v[4], b1v[4];
#pragma unroll
    for (int ni = 0; ni < 4; ++ni) {
        const int n = ncolbase + ni * 16 + fr;
        bv[ni]  = bias[sid * D_ + n];
        sv[ni]  = scemb[sid * D_ + n];
        b0v[ni] = bremb[0 * D_ + n];
        b1v[ni] = bremb[1 * D_ + n];
    }

    const size_t MIDOFF = (size_t)B_ * S_ * D_;
    float colsum[4] = {0.f, 0.f, 0.f, 0.f};

#pragma unroll
    for (int mi = 0; mi < 4; ++mi) {
        const int mrow0 = mt * FBM + wm * 64 + mi * 16 + fg * 4;
        float mk[4];
#pragma unroll
        for (int r = 0; r < 4; ++r)
            mk[r] = (mask[(size_t)bb * S_ + mrow0 + r] > 0) ? 1.f : 0.f;
#pragma unroll
        for (int ni = 0; ni < 4; ++ni) {
            const int n = ncolbase + ni * 16 + fr;
#pragma unroll
            for (int r = 0; r < 4; ++r) {
                const float v = acc[mi][ni][r] + bv[ni];
                const float o = v / (1.f + __expf(-v)) + sv[ni];
                const size_t idx = ((size_t)bb * S_ + (size_t)(mrow0 + r)) * D_ + n;
                __builtin_nontemporal_store(o + b0v[ni], &out[idx]);
                __builtin_nontemporal_store(o + b1v[ni], &out[MIDOFF + idx]);
                colsum[ni] += mk[r] * o;
            }
        }
    }

#pragma unroll
    for (int ni = 0; ni < 4; ++ni) {
        float s = colsum[ni];
        s += __shfl_xor(s, 16);
        s += __shfl_xor(s, 32);
        if (fg == 0)
            atomicAdd(&ws[(size_t)bb * D_ + (ncolbase + ni * 16 + fr)], s);
    }
}

__global__ void finalize(const int* __restrict__ mask,
                         const float* __restrict__ ws,
                         const float* __restrict__ bremb,
                         float* __restrict__ out)
{
    const int b = blockIdx.x;
    const int tid = threadIdx.x;

    int c = 0;
    for (int s = tid; s < S_; s += 256)
        c += (mask[(size_t)b * S_ + s] > 0) ? 1 : 0;
#pragma unroll
    for (int m = 1; m < 64; m <<= 1)
        c += __shfl_xor(c, m);

    __shared__ int part[4];
    if ((tid & 63) == 0) part[tid >> 6] = c;
    __syncthreads();
    const float denom = fmaxf((float)(part[0] + part[1] + part[2] + part[3]), 1e-6f);
    const float inv = 1.f / denom;

    const size_t LOWOFF = (size_t)2 * B_ * S_ * D_;
    for (int e = tid; e < D_; e += 256)
        out[LOWOFF + (size_t)b * D_ + e] = ws[(size_t)b * D_ + e] * inv + bremb[2 * D_ + e];
}

extern "C" void kernel_launch(void* const* d_in, const int* in_sizes, int n_in,
                              void* d_out, int out_size, void* d_ws, size_t ws_size,
                              hipStream_t stream) {
    const float* midi     = (const float*)d_in[0];
    const int*   scale_id = (const int*)d_in[1];
    const int*   mask     = (const int*)d_in[2];
    const float* W        = (const float*)d_in[3];
    const float* bias     = (const float*)d_in[4];
    const float* scemb    = (const float*)d_in[5];
    const float* bremb    = (const float*)d_in[6];
    float* out = (float*)d_out;
    float* colws = (float*)d_ws;

    const size_t COLWS_B = (size_t)B_ * D_ * sizeof(float);            // 128 KB
    const size_t WBF_B   = (size_t)3 * D_ * D_ * sizeof(short);        // 6 MB
    const size_t ABF_B   = (size_t)B_ * S_ * D_ * sizeof(short);       // 128 MB
    const size_t need    = COLWS_B + WBF_B + ABF_B;

    hipMemsetAsync(colws, 0, COLWS_B, stream);

    if (ws_size >= need) {
        __hip_bfloat16* wBf = (__hip_bfloat16*)((char*)d_ws + COLWS_B);
        __hip_bfloat16* aBf = (__hip_bfloat16*)((char*)d_ws + COLWS_B + WBF_B);
        cvt_bf16<<<dim3(2048), dim3(256), 0, stream>>>(
            (const float4v*)midi, (bf16x8*)aBf, (B_ * S_ * D_) / 8);
        cvt_bf16<<<dim3(512), dim3(256), 0, stream>>>(
            (const float4v*)W, (bf16x8*)wBf, (3 * D_ * D_) / 8);
        fused_gemm_bf16<<<dim3(B_ * (S_ / BM) * (D_ / BN)), dim3(512), 0, stream>>>(
            aBf, wBf, scale_id, mask, bias, scemb, bremb, out, colws);
    } else {
        fused_gemm_f32<<<dim3(B_ * (S_ / FBM) * (D_ / FBN)), dim3(256), 0, stream>>>(
            midi, scale_id, mask, W, bias, scemb, bremb, out, colws);
    }

    finalize<<<dim3(B_), dim3(256), 0, stream>>>(mask, colws, bremb, out);
}

// Round 13
// 300.957 us; speedup vs baseline: 1.1261x; 1.1261x over previous
//
#include <hip/hip_runtime.h>
#include <hip/hip_bf16.h>

#define B_ 32
#define S_ 2048
#define D_ 1024

// 256x256 tile, BK=64, 8 waves (2Mx4N), double-buffered 128KB LDS,
// ONE barrier per K-tile (R11-proven best: 309 us total).
#define BM 256
#define BN 256
#define BK 64
#define NKT (D_ / BK)   // 16 K-tiles

typedef __attribute__((ext_vector_type(8))) short bf16x8;
typedef __attribute__((ext_vector_type(4))) float f32x4;
typedef __attribute__((ext_vector_type(4))) float float4v;

#define AS1 __attribute__((address_space(1)))
#define AS3 __attribute__((address_space(3)))

// f32 -> bf16 round-to-nearest-even on raw bits
__device__ __forceinline__ short f2bf(float f) {
    union { float f; unsigned u; } uf;
    uf.f = f;
    unsigned u = uf.u;
    u += 0x7FFFu + ((u >> 16) & 1u);
    return (short)(u >> 16);
}

// ---------------- prep: zero colws + cvt A + cvt W in ONE dispatch ---------
__global__ __launch_bounds__(256) void prep(
    const float4v* __restrict__ midi4,   // midi as float4 pairs
    const float4v* __restrict__ W4,      // W as float4 pairs
    bf16x8* __restrict__ aBf8,
    bf16x8* __restrict__ wBf8,
    float4v* __restrict__ colws4)
{
    const int NA = (B_ * S_ * D_) / 8;     // A chunks (8 f32 each)
    const int NW = (3 * D_ * D_) / 8;      // W chunks
    const int NC = (B_ * D_) / 4;          // colws float4 zeros
    const int stride = gridDim.x * blockDim.x;
    int i0 = blockIdx.x * blockDim.x + threadIdx.x;

    for (int c = i0; c < NC; c += stride)
        colws4[c] = (float4v){0.f, 0.f, 0.f, 0.f};

    for (int i = i0; i < NA + NW; i += stride) {
        const float4v* src;
        bf16x8* dst;
        int j;
        if (i < NA) { src = midi4; dst = aBf8; j = i; }
        else        { src = W4;    dst = wBf8; j = i - NA; }
        float4v a = src[2 * j], b = src[2 * j + 1];
        bf16x8 v;
#pragma unroll
        for (int k = 0; k < 4; ++k) {
            v[k]     = f2bf(a[k]);
            v[4 + k] = f2bf(b[k]);
        }
        dst[j] = v;
    }
}

// ============================================================================
// R11 gemm VERBATIM (best measured): stage tile t+1 || compute tile t
// (compiler-scheduled 8 gll + 48 ds_read + 64 MFMA), one vmcnt(0)+s_barrier
// boundary per K-tile. LDS rows half-permuted (half h = global rows with
// bit5==h); byte swizzle stored = logical ^ ((row&7)<<4) via pre-swizzled
// global source.
// ============================================================================

#define STAGE_A(nb, h, kt) do {                                               \
    _Pragma("unroll")                                                         \
    for (int j_ = 0; j_ < 2; ++j_) {                                          \
        const int base_ = (h) * 128 + j_ * 64 + wid * 8;                      \
        const int grow_ = j_ * 128 + (h) * 64 + wid * 8 + lrow8;              \
        const __hip_bfloat16* g_ = aBase + (size_t)grow_ * D_ + (kt) * BK + (scb >> 1); \
        __builtin_amdgcn_global_load_lds((const AS1 unsigned int*)g_,         \
            (AS3 unsigned int*)&As[nb][base_ * 64], 16, 0, 0);                \
    } } while (0)

#define STAGE_B(nb, h, kt) do {                                               \
    _Pragma("unroll")                                                         \
    for (int j_ = 0; j_ < 2; ++j_) {                                          \
        const int base_ = (h) * 128 + j_ * 64 + wid * 8;                      \
        const int grow_ = base_ + lrow8;                                      \
        const __hip_bfloat16* g_ = bBase + (size_t)grow_ * D_ + (kt) * BK + (scb >> 1); \
        __builtin_amdgcn_global_load_lds((const AS1 unsigned int*)g_,         \
            (AS3 unsigned int*)&Bs[nb][base_ * 64], 16, 0, 0);                \
    } } while (0)

#define COMPUTE(cur, mh, bh) do {                                             \
    bf16x8 af_[4][2], bv_[2][2];                                              \
    _Pragma("unroll")                                                         \
    for (int mi_ = 0; mi_ < 4; ++mi_) {                                       \
        const int l_ = (mh) * 128 + wm * 64 + mi_ * 16 + fr;                  \
        _Pragma("unroll")                                                     \
        for (int kk_ = 0; kk_ < 2; ++kk_) {                                   \
            const int byt_ = l_ * 128 + ((kk_ * 64 + fg * 16) ^ ((l_ & 7) << 4)); \
            af_[mi_][kk_] = *(const bf16x8*)((const char*)&As[cur][0] + byt_); \
        }                                                                     \
    }                                                                         \
    _Pragma("unroll")                                                         \
    for (int ni_ = 0; ni_ < 2; ++ni_) {                                       \
        const int l_ = (bh) * 128 + wn * 32 + ni_ * 16 + fr;                  \
        _Pragma("unroll")                                                     \
        for (int kk_ = 0; kk_ < 2; ++kk_) {                                   \
            const int byt_ = l_ * 128 + ((kk_ * 64 + fg * 16) ^ ((l_ & 7) << 4)); \
            bv_[ni_][kk_] = *(const bf16x8*)((const char*)&Bs[cur][0] + byt_); \
        }                                                                     \
    }                                                                         \
    __builtin_amdgcn_s_setprio(1);                                            \
    _Pragma("unroll")                                                         \
    for (int mi_ = 0; mi_ < 4; ++mi_)                                         \
        _Pragma("unroll")                                                     \
        for (int ni_ = 0; ni_ < 2; ++ni_)                                     \
            _Pragma("unroll")                                                 \
            for (int kk_ = 0; kk_ < 2; ++kk_)                                 \
                acc[(mh) * 4 + mi_][(bh) * 2 + ni_] =                         \
                    __builtin_amdgcn_mfma_f32_16x16x32_bf16(                  \
                        af_[mi_][kk_], bv_[ni_][kk_],                         \
                        acc[(mh) * 4 + mi_][(bh) * 2 + ni_], 0, 0, 0);        \
    __builtin_amdgcn_s_setprio(0);                                            \
    } while (0)

#define BOUND() do {                                          \
    asm volatile("s_waitcnt vmcnt(0)" ::: "memory");          \
    asm volatile("s_barrier" ::: "memory"); } while (0)

#define BODY(X, Y, kn) do {                                                   \
    STAGE_B(Y, 0, kn); STAGE_A(Y, 0, kn); STAGE_B(Y, 1, kn); STAGE_A(Y, 1, kn); \
    COMPUTE(X, 0, 0); COMPUTE(X, 0, 1); COMPUTE(X, 1, 0); COMPUTE(X, 1, 1);   \
    BOUND();                                                                  \
} while (0)

#define BODY_LAST(X) do {                                                     \
    COMPUTE(X, 0, 0); COMPUTE(X, 0, 1); COMPUTE(X, 1, 0); COMPUTE(X, 1, 1);   \
} while (0)

__global__ __launch_bounds__(512, 2) void fused_gemm_bf16(
    const __hip_bfloat16* __restrict__ aBf,   // [B][S][D] bf16 (pre-converted)
    const __hip_bfloat16* __restrict__ wBf,   // [3][D][D] bf16 (pre-converted)
    const int*   __restrict__ scale_id,
    const int*   __restrict__ mask,
    const float* __restrict__ bias,
    const float* __restrict__ scemb,
    const float* __restrict__ bremb,
    float*       __restrict__ out,
    float*       __restrict__ colws)
{
    __shared__ __align__(16) short As[2][BM * BK];   // 2 x 32 KB
    __shared__ __align__(16) short Bs[2][BM * BK];   // 2 x 32 KB

    const int tid = threadIdx.x;
    const int lane = tid & 63;
    const int wid = tid >> 6;          // 0..7
    const int wm = wid >> 2;           // 0..1 (M)
    const int wn = wid & 3;            // 0..3 (N)

    // chunked XCD swizzle (NWG = 1024, divisible by 8)
    const int NTI = D_ / BN;  // 4
    const int MTI = S_ / BM;  // 8
    const int NWG = B_ * MTI * NTI;
    const int CPX = NWG / 8;
    int lid = ((int)blockIdx.x % 8) * CPX + ((int)blockIdx.x / 8);
    int nt = lid % NTI;
    int mt = (lid / NTI) % MTI;
    int bb = lid / (NTI * MTI);

    const int sid = scale_id[bb];
    const __hip_bfloat16* aBase = aBf + ((size_t)bb * S_ + (size_t)mt * BM) * D_;
    const __hip_bfloat16* bBase = wBf + ((size_t)sid * D_ + (size_t)nt * BN) * D_;

    // staging lane geometry: per issue, wave covers 8 LDS rows (64 lanes x 16B)
    const int lrow8 = lane >> 3;                           // 0..7
    const int scb = ((lane & 7) * 16) ^ (lrow8 << 4);      // pre-swizzled col-byte

    const int fr = lane & 15;
    const int fg = lane >> 4;

    f32x4 acc[8][4];
#pragma unroll
    for (int mi = 0; mi < 8; ++mi)
#pragma unroll
        for (int ni = 0; ni < 4; ++ni)
            acc[mi][ni] = (f32x4){0.f, 0.f, 0.f, 0.f};

    // prologue: tile 0 -> buf 0; full retire before first read
    STAGE_B(0, 0, 0); STAGE_A(0, 0, 0); STAGE_B(0, 1, 0); STAGE_A(0, 1, 0);
    BOUND();

#pragma unroll 1
    for (int kt = 0; kt < NKT - 2; kt += 2) {
        BODY(0, 1, kt + 1);
        BODY(1, 0, kt + 2);
    }
    BODY(0, 1, NKT - 1);   // tile 14 (buf0), stages tile 15 -> buf1, boundary
    BODY_LAST(1);          // tile 15 (buf1), no staging

    __syncthreads();       // drain; LDS reusable

    // ---- epilogue phase 1: silu + scale_embed in-register, masked colsums ----
    const int colb = nt * BN;
    float bv2[2][2], sv2[2][2];
#pragma unroll
    for (int bh = 0; bh < 2; ++bh)
#pragma unroll
        for (int ni = 0; ni < 2; ++ni) {
            const int n = colb + bh * 128 + wn * 32 + ni * 16 + fr;
            bv2[bh][ni] = bias[sid * D_ + n];
            sv2[bh][ni] = scemb[sid * D_ + n];
        }

    float colsum[2][2] = {{0.f, 0.f}, {0.f, 0.f}};
#pragma unroll
    for (int mig = 0; mig < 8; ++mig) {
        const int mrow0 = mt * BM + wm * 128 + mig * 16 + fg * 4;
        float mk[4];
#pragma unroll
        for (int r = 0; r < 4; ++r)
            mk[r] = (mask[(size_t)bb * S_ + mrow0 + r] > 0) ? 1.f : 0.f;
#pragma unroll
        for (int bh = 0; bh < 2; ++bh)
#pragma unroll
            for (int ni = 0; ni < 2; ++ni)
#pragma unroll
                for (int r = 0; r < 4; ++r) {
                    const float v = acc[mig][bh * 2 + ni][r] + bv2[bh][ni];
                    const float o = v / (1.f + __expf(-v)) + sv2[bh][ni];
                    acc[mig][bh * 2 + ni][r] = o;
                    colsum[bh][ni] += mk[r] * o;
                }
    }

#pragma unroll
    for (int bh = 0; bh < 2; ++bh)
#pragma unroll
        for (int ni = 0; ni < 2; ++ni) {
            float s = colsum[bh][ni];
            s += __shfl_xor(s, 16);
            s += __shfl_xor(s, 32);
            if (fg == 0)
                atomicAdd(&colws[(size_t)bb * D_ + (colb + bh * 128 + wn * 32 + ni * 16 + fr)], s);
        }

    // ---- epilogue phase 2: LDS bounce -> full-row contiguous float4 stores ----
    float* ldsF = (float*)&As[0][0];
    const float4v b0 = *(const float4v*)&bremb[0 * D_ + colb + lane * 4];
    const float4v b1 = *(const float4v*)&bremb[1 * D_ + colb + lane * 4];
    const size_t MIDOFF = (size_t)B_ * S_ * D_;

#pragma unroll
    for (int mig = 0; mig < 8; ++mig) {
#pragma unroll
        for (int bh = 0; bh < 2; ++bh)
#pragma unroll
            for (int ni = 0; ni < 2; ++ni)
#pragma unroll
                for (int r = 0; r < 4; ++r)
                    ldsF[(wm * 16 + fg * 4 + r) * 260 + bh * 128 + wn * 32 + ni * 16 + fr] =
                        acc[mig][bh * 2 + ni][r];
        __syncthreads();

#pragma unroll
        for (int k = 0; k < 4; ++k) {
            const int lr = wid * 4 + k;                      // 0..31, uniform per wave
            const int grow = mt * BM + (lr >> 4) * 128 + mig * 16 + (lr & 15);
            const size_t rowbase = ((size_t)bb * S_ + grow) * D_ + colb;
            float4v v = *(const float4v*)&ldsF[lr * 260 + lane * 4];
            __builtin_nontemporal_store(v + b0, (float4v*)&out[rowbase + lane * 4]);
            __builtin_nontemporal_store(v + b1, (float4v*)&out[MIDOFF + rowbase + lane * 4]);
        }
        __syncthreads();
    }
}

// ---------------- fallback path (f32 reg-staging, 128^2, 2-barrier) --------
#define FBM 128
#define FBN 128
#define FBK 64
#define FNK (D_ / FBK)

__global__ __launch_bounds__(256, 2) void fused_gemm_f32(
    const float* __restrict__ midi,
    const int*   __restrict__ scale_id,
    const int*   __restrict__ mask,
    const float* __restrict__ W,
    const float* __restrict__ bias,
    const float* __restrict__ scemb,
    const float* __restrict__ bremb,
    float*       __restrict__ out,
    float*       __restrict__ ws)
{
    __shared__ __align__(16) short Asf[FBM * FBK];
    __shared__ __align__(16) short Bsf[FBM * FBK];

    const int tid = threadIdx.x;
    const int NTI = D_ / FBN;
    const int MTI = S_ / FBM;
    const int NWG = B_ * MTI * NTI;
    const int CPX = NWG / 8;
    int lid = ((int)blockIdx.x % 8) * CPX + ((int)blockIdx.x / 8);
    int nt = lid % NTI;
    int mt = (lid / NTI) % MTI;
    int bb = lid / (NTI * MTI);

    const int sid = scale_id[bb];
    const float* aBase = midi + ((size_t)bb * S_ + (size_t)mt * FBM) * D_;
    const float* bBase = W + ((size_t)sid * D_ + (size_t)nt * FBN) * D_;

    const int r0 = tid >> 3;
    const int kp = (tid & 7) * 8;

    float4v aL[4], aH[4], bL[4], bH[4];

    auto load_regs = [&](int kt) {
        const int kc = kt * FBK + kp;
#pragma unroll
        for (int i = 0; i < 4; ++i) {
            const float* pa = aBase + (size_t)(r0 + 32 * i) * D_ + kc;
            aL[i] = *(const float4v*)pa;
            aH[i] = *(const float4v*)(pa + 4);
            const float* pb = bBase + (size_t)(r0 + 32 * i) * D_ + kc;
            bL[i] = *(const float4v*)pb;
            bH[i] = *(const float4v*)(pb + 4);
        }
    };

    auto write_lds = [&]() {
#pragma unroll
        for (int i = 0; i < 4; ++i) {
            const int row = r0 + 32 * i;
            const int off = (row * FBK + kp) ^ ((row & 7) << 3);
            bf16x8 va, vb;
#pragma unroll
            for (int j = 0; j < 4; ++j) {
                va[j]     = f2bf(aL[i][j]);
                va[4 + j] = f2bf(aH[i][j]);
                vb[j]     = f2bf(bL[i][j]);
                vb[4 + j] = f2bf(bH[i][j]);
            }
            *(bf16x8*)&Asf[off] = va;
            *(bf16x8*)&Bsf[off] = vb;
        }
    };

    f32x4 acc[4][4];
#pragma unroll
    for (int mi = 0; mi < 4; ++mi)
#pragma unroll
        for (int ni = 0; ni < 4; ++ni)
            acc[mi][ni] = (f32x4){0.f, 0.f, 0.f, 0.f};

    const int lane = tid & 63;
    const int wid = tid >> 6;
    const int wm = wid >> 1, wn = wid & 1;
    const int fr = lane & 15;
    const int fg = lane >> 4;

    load_regs(0);
    write_lds();
    __syncthreads();

    for (int kt = 0; kt < FNK; ++kt) {
        if (kt + 1 < FNK) load_regs(kt + 1);
#pragma unroll
        for (int kk = 0; kk < 2; ++kk) {
            bf16x8 af[4], bfr[4];
#pragma unroll
            for (int mi = 0; mi < 4; ++mi) {
                const int row = wm * 64 + mi * 16 + fr;
                const int off = (row * FBK + kk * 32 + fg * 8) ^ ((row & 7) << 3);
                af[mi] = *(const bf16x8*)&Asf[off];
            }
#pragma unroll
            for (int ni = 0; ni < 4; ++ni) {
                const int row = wn * 64 + ni * 16 + fr;
                const int off = (row * FBK + kk * 32 + fg * 8) ^ ((row & 7) << 3);
                bfr[ni] = *(const bf16x8*)&Bsf[off];
            }
#pragma unroll
            for (int mi = 0; mi < 4; ++mi)
#pragma unroll
                for (int ni = 0; ni < 4; ++ni)
                    acc[mi][ni] = __builtin_amdgcn_mfma_f32_16x16x32_bf16(
                        af[mi], bfr[ni], acc[mi][ni], 0, 0, 0);
        }
        __syncthreads();
        if (kt + 1 < FNK) write_lds();
        __syncthreads();
    }

    const int ncolbase = nt * FBN + wn * 64;
    float bv[4], sv[4], b0v[4], b1v[4];
#pragma unroll
    for (int ni = 0; ni < 4; ++ni) {
        const int n = ncolbase + ni * 16 + fr;
        bv[ni]  = bias[sid * D_ + n];
        sv[ni]  = scemb[sid * D_ + n];
        b0v[ni] = bremb[0 * D_ + n];
        b1v[ni] = bremb[1 * D_ + n];
    }

    const size_t MIDOFF = (size_t)B_ * S_ * D_;
    float colsum[4] = {0.f, 0.f, 0.f, 0.f};

#pragma unroll
    for (int mi = 0; mi < 4; ++mi) {
        const int mrow0 = mt * FBM + wm * 64 + mi * 16 + fg * 4;
        float mk[4];
#pragma unroll
        for (int r = 0; r < 4; ++r)
            mk[r] = (mask[(size_t)bb * S_ + mrow0 + r] > 0) ? 1.f : 0.f;
#pragma unroll
        for (int ni = 0; ni < 4; ++ni) {
            const int n = ncolbase + ni * 16 + fr;
#pragma unroll
            for (int r = 0; r < 4; ++r) {
                const float v = acc[mi][ni][r] + bv[ni];
                const float o = v / (1.f + __expf(-v)) + sv[ni];
                const size_t idx = ((size_t)bb * S_ + (size_t)(mrow0 + r)) * D_ + n;
                __builtin_nontemporal_store(o + b0v[ni], &out[idx]);
                __builtin_nontemporal_store(o + b1v[ni], &out[MIDOFF + idx]);
                colsum[ni] += mk[r] * o;
            }
        }
    }

#pragma unroll
    for (int ni = 0; ni < 4; ++ni) {
        float s = colsum[ni];
        s += __shfl_xor(s, 16);
        s += __shfl_xor(s, 32);
        if (fg == 0)
            atomicAdd(&ws[(size_t)bb * D_ + (ncolbase + ni * 16 + fr)], s);
    }
}

__global__ void finalize(const int* __restrict__ mask,
                         const float* __restrict__ ws,
                         const float* __restrict__ bremb,
                         float* __restrict__ out)
{
    const int b = blockIdx.x;
    const int tid = threadIdx.x;

    int c = 0;
    for (int s = tid; s < S_; s += 256)
        c += (mask[(size_t)b * S_ + s] > 0) ? 1 : 0;
#pragma unroll
    for (int m = 1; m < 64; m <<= 1)
        c += __shfl_xor(c, m);

    __shared__ int part[4];
    if ((tid & 63) == 0) part[tid >> 6] = c;
    __syncthreads();
    const float denom = fmaxf((float)(part[0] + part[1] + part[2] + part[3]), 1e-6f);
    const float inv = 1.f / denom;

    const size_t LOWOFF = (size_t)2 * B_ * S_ * D_;
    for (int e = tid; e < D_; e += 256)
        out[LOWOFF + (size_t)b * D_ + e] = ws[(size_t)b * D_ + e] * inv + bremb[2 * D_ + e];
}

extern "C" void kernel_launch(void* const* d_in, const int* in_sizes, int n_in,
                              void* d_out, int out_size, void* d_ws, size_t ws_size,
                              hipStream_t stream) {
    const float* midi     = (const float*)d_in[0];
    const int*   scale_id = (const int*)d_in[1];
    const int*   mask     = (const int*)d_in[2];
    const float* W        = (const float*)d_in[3];
    const float* bias     = (const float*)d_in[4];
    const float* scemb    = (const float*)d_in[5];
    const float* bremb    = (const float*)d_in[6];
    float* out = (float*)d_out;
    float* colws = (float*)d_ws;

    const size_t COLWS_B = (size_t)B_ * D_ * sizeof(float);            // 128 KB
    const size_t WBF_B   = (size_t)3 * D_ * D_ * sizeof(short);        // 6 MB
    const size_t ABF_B   = (size_t)B_ * S_ * D_ * sizeof(short);       // 128 MB
    const size_t need    = COLWS_B + WBF_B + ABF_B;

    if (ws_size >= need) {
        __hip_bfloat16* wBf = (__hip_bfloat16*)((char*)d_ws + COLWS_B);
        __hip_bfloat16* aBf = (__hip_bfloat16*)((char*)d_ws + COLWS_B + WBF_B);
        // single prep dispatch: zero colws + cvt A + cvt W
        prep<<<dim3(2048), dim3(256), 0, stream>>>(
            (const float4v*)midi, (const float4v*)W,
            (bf16x8*)aBf, (bf16x8*)wBf, (float4v*)colws);
        fused_gemm_bf16<<<dim3(B_ * (S_ / BM) * (D_ / BN)), dim3(512), 0, stream>>>(
            aBf, wBf, scale_id, mask, bias, scemb, bremb, out, colws);
    } else {
        hipMemsetAsync(colws, 0, COLWS_B, stream);
        fused_gemm_f32<<<dim3(B_ * (S_ / FBM) * (D_ / FBN)), dim3(256), 0, stream>>>(
            midi, scale_id, mask, W, bias, scemb, bremb, out, colws);
    }

    finalize<<<dim3(B_), dim3(256), 0, stream>>>(mask, colws, bremb, out);
}